// Round 1
// baseline (418.356 us; speedup 1.0000x reference)
//
#include <hip/hip_runtime.h>

// MI355X / gfx950. bf16 MFMA implementation of BERT-style attention with
// relu^2 "softmax". Layout facts (HW-verified per guide):
//   mfma_f32_16x16x32_bf16: A lane l holds A[m=l&15][k=(l>>4)*8+j], j=0..7
//                           B lane l holds B[k=(l>>4)*8+j][n=l&15]
//                           C/D lane l reg r holds D[row=(l>>4)*4+r][col=l&15]
// => both operands want "8 contiguous k from row (lane&15)" when the n-side
//    matrix is available row-major [n][k] (true for W, K, and V^T).

typedef __bf16 bf16x8 __attribute__((ext_vector_type(8)));
typedef __bf16 bf16x4 __attribute__((ext_vector_type(4)));
typedef float  f32x4  __attribute__((ext_vector_type(4)));
typedef float  floatx4 __attribute__((ext_vector_type(4)));

#define MFMA16(a, b, c) __builtin_amdgcn_mfma_f32_16x16x32_bf16(a, b, c, 0, 0, 0)

// ---------------------------------------------------------------------------
// Kernel A: out = x @ W.T + bias, written as bf16 in attention-friendly layout.
//   mode 0: out[((b*16+h)*2048 + s)*64 + d]   (Q and K)
//   mode 2: out[((b*16+h)*64 + d)*2048 + s]   (V transposed)
// x: [8192,1024] f32, W: [1024,1024] f32 row-major (row = out feature).
// Tile 128x128, BK=64, 4 waves in 2x2 arrangement, 64x64 per wave.
// ---------------------------------------------------------------------------
__global__ __launch_bounds__(256) void qkv_gemm_kernel(
    const float* __restrict__ X, const float* __restrict__ W,
    const float* __restrict__ bias, __bf16* __restrict__ outp, int mode)
{
    __shared__ __bf16 As[128][72];   // +8 pad: row stride 144B -> 2-way (free)
    __shared__ __bf16 Bs[128][72];

    const int tid  = threadIdx.x;
    const int lane = tid & 63;
    const int wave = tid >> 6;
    const int wm   = (wave >> 1) * 64;
    const int wn   = (wave & 1) * 64;
    const int quad = lane >> 4;
    const int l16  = lane & 15;
    const int m0   = blockIdx.y * 128;
    const int n0   = blockIdx.x * 128;

    f32x4 acc[4][4] = {};

    for (int k0 = 0; k0 < 1024; k0 += 64) {
        __syncthreads();
        // Stage 128x64 fp32 tiles of X and W as bf16. 16 float4/row.
        #pragma unroll
        for (int i = 0; i < 8; ++i) {
            int flat = i * 256 + tid;
            int row  = flat >> 4;
            int c4   = (flat & 15) << 2;
            floatx4 a = *(const floatx4*)(X + (size_t)(m0 + row) * 1024 + k0 + c4);
            floatx4 b = *(const floatx4*)(W + (size_t)(n0 + row) * 1024 + k0 + c4);
            bf16x4 ab, bb;
            ab[0] = (__bf16)a[0]; ab[1] = (__bf16)a[1];
            ab[2] = (__bf16)a[2]; ab[3] = (__bf16)a[3];
            bb[0] = (__bf16)b[0]; bb[1] = (__bf16)b[1];
            bb[2] = (__bf16)b[2]; bb[3] = (__bf16)b[3];
            *(bf16x4*)&As[row][c4] = ab;     // 8B ds_write, aligned
            *(bf16x4*)&Bs[row][c4] = bb;
        }
        __syncthreads();

        #pragma unroll
        for (int kk = 0; kk < 64; kk += 32) {
            bf16x8 af[4], bfr[4];
            #pragma unroll
            for (int mi = 0; mi < 4; ++mi)
                af[mi] = *(const bf16x8*)&As[wm + mi * 16 + l16][kk + quad * 8];
            #pragma unroll
            for (int ni = 0; ni < 4; ++ni)
                bfr[ni] = *(const bf16x8*)&Bs[wn + ni * 16 + l16][kk + quad * 8];
            #pragma unroll
            for (int mi = 0; mi < 4; ++mi)
                #pragma unroll
                for (int ni = 0; ni < 4; ++ni)
                    acc[mi][ni] = MFMA16(af[mi], bfr[ni], acc[mi][ni]);
        }
    }

    // Epilogue: + bias, cast bf16, scatter to head layout.
    #pragma unroll
    for (int mi = 0; mi < 4; ++mi) {
        #pragma unroll
        for (int ni = 0; ni < 4; ++ni) {
            int n = n0 + wn + ni * 16 + l16;    // 0..1023
            float bv = bias[n];
            int h = n >> 6;
            int d = n & 63;
            #pragma unroll
            for (int r = 0; r < 4; ++r) {
                int m = m0 + wm + mi * 16 + quad * 4 + r;   // 0..8191
                int b = m >> 11;
                int s = m & 2047;
                float v = acc[mi][ni][r] + bv;
                __bf16 hv = (__bf16)v;
                size_t idx;
                if (mode == 2) idx = ((size_t)(b * 16 + h) * 64 + d) * 2048 + s;
                else           idx = ((size_t)(b * 16 + h) * 2048 + s) * 64 + d;
                outp[idx] = hv;
            }
        }
    }
}

// ---------------------------------------------------------------------------
// Kernel B: per (bh, q-tile of 128): ctx = relu^2(Q K^T / 8 + mask) @ V.
// 4 waves, each owning 32 q-rows. Q frags live in registers (loaded once).
// Per 128-wide k-tile: stage K [128][64] and Vt [64][128] in LDS; scores via
// MFMA; p = relu^2 written bf16 to wave-private Ps rows (C-layout -> A-layout
// via LDS, no cross-wave barrier needed); then P @ V accumulated in fp32.
// ---------------------------------------------------------------------------
__global__ __launch_bounds__(256) void attn_kernel(
    const __bf16* __restrict__ Q, const __bf16* __restrict__ K,
    const __bf16* __restrict__ Vt, const float* __restrict__ mask,
    float* __restrict__ out)
{
    __shared__ __bf16 Ks[128][72];
    __shared__ __bf16 Vs[64][136];
    __shared__ __bf16 Ps[128][136];

    const int tid  = threadIdx.x;
    const int lane = tid & 63;
    const int wave = tid >> 6;
    const int quad = lane >> 4;
    const int l16  = lane & 15;
    const int bh   = blockIdx.y;
    const int b    = bh >> 4;
    const int h    = bh & 15;
    const int q0   = blockIdx.x * 128;

    const __bf16* Qb = Q  + (size_t)bh * 2048 * 64;
    const __bf16* Kb = K  + (size_t)bh * 2048 * 64;
    const __bf16* Vb = Vt + (size_t)bh * 64 * 2048;
    const float*  mb = mask + b * 2048;

    // Q fragments: rows wave*32 .. wave*32+31, head-dim K=64 in 2 chunks.
    bf16x8 aq[2][2];
    #pragma unroll
    for (int mi = 0; mi < 2; ++mi)
        #pragma unroll
        for (int kc = 0; kc < 2; ++kc)
            aq[mi][kc] = *(const bf16x8*)(Qb +
                (size_t)(q0 + wave * 32 + mi * 16 + l16) * 64 + kc * 32 + quad * 8);

    f32x4 co[2][4] = {};   // ctx accumulator: 32 rows x 64 d per wave

    for (int k0 = 0; k0 < 2048; k0 += 128) {
        __syncthreads();   // protect Ks/Vs from previous iteration's readers
        #pragma unroll
        for (int i = 0; i < 4; ++i) {          // K-tile: 128 rows x 64
            int flat = i * 256 + tid;
            int row  = flat >> 3;
            int c8   = (flat & 7) << 3;
            *(bf16x8*)&Ks[row][c8] =
                *(const bf16x8*)(Kb + (size_t)(k0 + row) * 64 + c8);
        }
        #pragma unroll
        for (int i = 0; i < 4; ++i) {          // Vt-tile: 64 rows x 128
            int flat = i * 256 + tid;
            int row  = flat >> 4;
            int c8   = (flat & 15) << 3;
            *(bf16x8*)&Vs[row][c8] =
                *(const bf16x8*)(Vb + (size_t)row * 2048 + k0 + c8);
        }
        __syncthreads();

        // Scores: 32 q-rows x 128 keys per wave, K-dim 64.
        f32x4 sacc[2][8] = {};
        #pragma unroll
        for (int kc = 0; kc < 2; ++kc) {
            #pragma unroll
            for (int ni = 0; ni < 8; ++ni) {
                bf16x8 bk = *(const bf16x8*)&Ks[ni * 16 + l16][kc * 32 + quad * 8];
                #pragma unroll
                for (int mi = 0; mi < 2; ++mi)
                    sacc[mi][ni] = MFMA16(aq[mi][kc], bk, sacc[mi][ni]);
            }
        }

        // p = relu(s*0.125 + mask)^2 -> bf16 into wave-private Ps rows.
        #pragma unroll
        for (int ni = 0; ni < 8; ++ni) {
            int col = ni * 16 + l16;
            float mk = mb[k0 + col];
            #pragma unroll
            for (int mi = 0; mi < 2; ++mi)
                #pragma unroll
                for (int r = 0; r < 4; ++r) {
                    float sc = sacc[mi][ni][r] * 0.125f + mk;
                    sc = fmaxf(sc, 0.0f);
                    Ps[wave * 32 + mi * 16 + quad * 4 + r][col] = (__bf16)(sc * sc);
                }
        }
        // No barrier: each wave reads back only the rows it just wrote
        // (compiler inserts the lgkmcnt wait for the LDS RAW hazard).

        // ctx += P @ V. K-dim = 128 keys in 4 chunks of 32.
        #pragma unroll
        for (int kc = 0; kc < 4; ++kc) {
            bf16x8 ap[2], bv[4];
            #pragma unroll
            for (int mi = 0; mi < 2; ++mi)
                ap[mi] = *(const bf16x8*)&Ps[wave * 32 + mi * 16 + l16][kc * 32 + quad * 8];
            #pragma unroll
            for (int ni = 0; ni < 4; ++ni)
                bv[ni] = *(const bf16x8*)&Vs[ni * 16 + l16][kc * 32 + quad * 8];
            #pragma unroll
            for (int mi = 0; mi < 2; ++mi)
                #pragma unroll
                for (int ni = 0; ni < 4; ++ni)
                    co[mi][ni] = MFMA16(ap[mi], bv[ni], co[mi][ni]);
        }
    }

    // Epilogue: out[b][s][h*64+d] fp32.
    #pragma unroll
    for (int mi = 0; mi < 2; ++mi)
        #pragma unroll
        for (int ni = 0; ni < 4; ++ni)
            #pragma unroll
            for (int r = 0; r < 4; ++r) {
                int s = q0 + wave * 32 + mi * 16 + quad * 4 + r;
                int d = ni * 16 + l16;
                out[(((size_t)b * 2048 + s) * 16 + h) * 64 + d] = co[mi][ni][r];
            }
}

// ---------------------------------------------------------------------------
extern "C" void kernel_launch(void* const* d_in, const int* in_sizes, int n_in,
                              void* d_out, int out_size, void* d_ws, size_t ws_size,
                              hipStream_t stream) {
    const float* hidden = (const float*)d_in[0];   // [4,2048,1024]
    const float* mask   = (const float*)d_in[1];   // [4,1,1,2048]
    const float* Wq     = (const float*)d_in[2];
    const float* bq     = (const float*)d_in[3];
    const float* Wk     = (const float*)d_in[4];
    const float* bk     = (const float*)d_in[5];
    const float* Wv     = (const float*)d_in[6];
    const float* bv     = (const float*)d_in[7];
    float* out = (float*)d_out;

    // Workspace: Q, K as [64][2048][64] bf16; V^T as [64][64][2048] bf16. 48 MB.
    __bf16* qws = (__bf16*)d_ws;
    __bf16* kws = qws + (size_t)64 * 2048 * 64;
    __bf16* vws = kws + (size_t)64 * 2048 * 64;

    dim3 gA(8, 64), blk(256);
    qkv_gemm_kernel<<<gA, blk, 0, stream>>>(hidden, Wq, bq, qws, 0);
    qkv_gemm_kernel<<<gA, blk, 0, stream>>>(hidden, Wk, bk, kws, 0);
    qkv_gemm_kernel<<<gA, blk, 0, stream>>>(hidden, Wv, bv, vws, 2);
    attn_kernel<<<dim3(16, 64), blk, 0, stream>>>(qws, kws, vws, mask, out);
}

// Round 2
// 333.034 us; speedup vs baseline: 1.2562x; 1.2562x over previous
//
#include <hip/hip_runtime.h>

// MI355X / gfx950. bf16 MFMA BERT attention with relu^2 "softmax".
// mfma_f32_16x16x32_bf16 layouts (HW-verified):
//   A: lane l holds A[m=l&15][k=(l>>4)*8+j]
//   B: lane l holds B[k=(l>>4)*8+j][n=l&15]
//   C/D: lane l reg r holds D[row=(l>>4)*4+r][col=l&15]
// Attention trick: compute S^T = K Q^T so C-layout rows = keys (contraction
// dim of PV). Lane's 4 regs = 4 consecutive keys -> vector b64 store into
// Ps[q][key]; PV A-frags then read b128 rows of Ps. Both transforms wide.

typedef __bf16 bf16x8 __attribute__((ext_vector_type(8)));
typedef __bf16 bf16x4 __attribute__((ext_vector_type(4)));
typedef float  f32x4  __attribute__((ext_vector_type(4)));
typedef float  floatx4 __attribute__((ext_vector_type(4)));

#define MFMA16(a, b, c) __builtin_amdgcn_mfma_f32_16x16x32_bf16(a, b, c, 0, 0, 0)

// async global->LDS, 16B per lane. LDS dest must be wave-uniform base
// (HW adds lane*16); global pointer is per-lane.
__device__ __forceinline__ void glds16(const __bf16* g, __bf16* l) {
    __builtin_amdgcn_global_load_lds(
        (const __attribute__((address_space(1))) void*)g,
        (__attribute__((address_space(3))) void*)l, 16, 0, 0);
}

// ---------------------------------------------------------------------------
// fp32 -> bf16 conversions for X (8M elems) and Wq/Wk/Wv (1M each).
// 2048 elems per block.
// ---------------------------------------------------------------------------
__global__ __launch_bounds__(256) void convert_kernel(
    const float* __restrict__ X, const float* __restrict__ Wq,
    const float* __restrict__ Wk, const float* __restrict__ Wv,
    __bf16* __restrict__ Xb, __bf16* __restrict__ Wqb,
    __bf16* __restrict__ Wkb, __bf16* __restrict__ Wvb)
{
    int blk = blockIdx.x;
    const float* src; __bf16* dst; size_t base;
    if (blk < 4096)      { src = X;  dst = Xb;  base = (size_t)blk * 2048; }
    else if (blk < 4608) { src = Wq; dst = Wqb; base = (size_t)(blk - 4096) * 2048; }
    else if (blk < 5120) { src = Wk; dst = Wkb; base = (size_t)(blk - 4608) * 2048; }
    else                 { src = Wv; dst = Wvb; base = (size_t)(blk - 5120) * 2048; }
    size_t off = base + (size_t)threadIdx.x * 8;
    floatx4 a = *(const floatx4*)(src + off);
    floatx4 c = *(const floatx4*)(src + off + 4);
    bf16x8 o;
    o[0] = (__bf16)a[0]; o[1] = (__bf16)a[1]; o[2] = (__bf16)a[2]; o[3] = (__bf16)a[3];
    o[4] = (__bf16)c[0]; o[5] = (__bf16)c[1]; o[6] = (__bf16)c[2]; o[7] = (__bf16)c[3];
    *(bf16x8*)(dst + off) = o;
}

// ---------------------------------------------------------------------------
// Fused QKV GEMM: out = Xb @ Wb.T + bias, bf16 in/out, glds staging with
// XOR-swizzled unpadded LDS (slot = chunk ^ (row&7)) for conflict-free
// b128 frag reads. blockIdx.x: 0-7 -> Q, 8-15 -> K, 16-23 -> V(transposed).
// Tile 128x128, BK=64, 4 waves 2x2, 64x64 per wave.
// ---------------------------------------------------------------------------
__global__ __launch_bounds__(256) void qkv_gemm_kernel(
    const __bf16* __restrict__ Xb,
    const __bf16* __restrict__ Wqb, const __bf16* __restrict__ Wkb,
    const __bf16* __restrict__ Wvb,
    const float* __restrict__ bq, const float* __restrict__ bk,
    const float* __restrict__ bv,
    __bf16* __restrict__ qws, __bf16* __restrict__ kws, __bf16* __restrict__ vws)
{
    __shared__ __bf16 As[128 * 64];
    __shared__ __bf16 Bs[128 * 64];

    const int tid  = threadIdx.x;
    const int lane = tid & 63;
    const int wave = tid >> 6;
    const int wm   = (wave >> 1) * 64;
    const int wn   = (wave & 1) * 64;
    const int quad = lane >> 4;
    const int l16  = lane & 15;
    const int m0   = blockIdx.y * 128;

    const int sel = blockIdx.x >> 3;
    const __bf16* Wb = (sel == 0) ? Wqb : (sel == 1) ? Wkb : Wvb;
    const float* bias = (sel == 0) ? bq : (sel == 1) ? bk : bv;
    __bf16* outp = (sel == 0) ? qws : (sel == 1) ? kws : vws;
    const int n0 = (blockIdx.x & 7) * 128;

    f32x4 acc[4][4] = {};

    for (int k0 = 0; k0 < 1024; k0 += 64) {
        __syncthreads();
        #pragma unroll
        for (int i = 0; i < 4; ++i) {
            int r = wave * 32 + i * 8 + (lane >> 3);      // tile row 0..127
            int c = (lane & 7) ^ (r & 7);                 // swizzled k-chunk
            glds16(Xb + (size_t)(m0 + r) * 1024 + k0 + c * 8,
                   &As[(wave * 32 + i * 8) * 64]);
            glds16(Wb + (size_t)(n0 + r) * 1024 + k0 + c * 8,
                   &Bs[(wave * 32 + i * 8) * 64]);
        }
        __syncthreads();

        #pragma unroll
        for (int kk8 = 0; kk8 < 8; kk8 += 4) {            // two K=32 steps
            bf16x8 af[4], bfr[4];
            #pragma unroll
            for (int mi = 0; mi < 4; ++mi)
                af[mi] = *(const bf16x8*)&As[(wm + mi * 16 + l16) * 64 +
                                             (((kk8 + quad) ^ (l16 & 7)) * 8)];
            #pragma unroll
            for (int ni = 0; ni < 4; ++ni)
                bfr[ni] = *(const bf16x8*)&Bs[(wn + ni * 16 + l16) * 64 +
                                              (((kk8 + quad) ^ (l16 & 7)) * 8)];
            #pragma unroll
            for (int mi = 0; mi < 4; ++mi)
                #pragma unroll
                for (int ni = 0; ni < 4; ++ni)
                    acc[mi][ni] = MFMA16(af[mi], bfr[ni], acc[mi][ni]);
        }
    }

    // Epilogue: + bias, cast bf16, scatter to head layout.
    #pragma unroll
    for (int mi = 0; mi < 4; ++mi) {
        #pragma unroll
        for (int ni = 0; ni < 4; ++ni) {
            int n = n0 + wn + ni * 16 + l16;              // 0..1023
            float bvv = bias[n];
            int h = n >> 6;
            int d = n & 63;
            #pragma unroll
            for (int r = 0; r < 4; ++r) {
                int m = m0 + wm + mi * 16 + quad * 4 + r; // 0..8191
                int b = m >> 11;
                int s = m & 2047;
                __bf16 hv = (__bf16)(acc[mi][ni][r] + bvv);
                size_t idx;
                if (sel == 2) idx = ((size_t)(b * 16 + h) * 64 + d) * 2048 + s;
                else          idx = ((size_t)(b * 16 + h) * 2048 + s) * 64 + d;
                outp[idx] = hv;
            }
        }
    }
}

// ---------------------------------------------------------------------------
// Attention: per (bh, 128-q tile): ctx = relu^2(Q K^T / 8 + mask) @ V.
// S computed TRANSPOSED (A=K frags from LDS, B=Q frags in registers).
// Ps[q][key] stride 136 (b64 writes & b128 reads both bank-balanced).
// K/V staged via glds with XOR swizzle.
// ---------------------------------------------------------------------------
__global__ __launch_bounds__(256) void attn_kernel(
    const __bf16* __restrict__ Q, const __bf16* __restrict__ K,
    const __bf16* __restrict__ Vt, const float* __restrict__ mask,
    float* __restrict__ out)
{
    __shared__ __bf16 Ks[128 * 64];    // [key][d]   swizzled, 16 KB
    __shared__ __bf16 Vs[64 * 128];    // [d][key]   swizzled, 16 KB
    __shared__ __bf16 Ps[128 * 136];   // [q][key]   padded,   34 KB

    const int tid  = threadIdx.x;
    const int lane = tid & 63;
    const int wave = tid >> 6;
    const int quad = lane >> 4;
    const int l16  = lane & 15;
    const int bh   = blockIdx.y;
    const int b    = bh >> 4;
    const int h    = bh & 15;
    const int q0   = blockIdx.x * 128;
    const int wq   = wave * 32;        // wave's q-rows within tile

    const __bf16* Qb = Q  + (size_t)bh * 2048 * 64;
    const __bf16* Kb = K  + (size_t)bh * 2048 * 64;
    const __bf16* Vb = Vt + (size_t)bh * 64 * 2048;
    const float*  mb = mask + b * 2048;

    // Q fragments (also serve as MFMA B operand for S^T — same per-lane data).
    bf16x8 aq[2][2];
    #pragma unroll
    for (int mi = 0; mi < 2; ++mi)
        #pragma unroll
        for (int kc = 0; kc < 2; ++kc)
            aq[mi][kc] = *(const bf16x8*)(Qb +
                (size_t)(q0 + wq + mi * 16 + l16) * 64 + kc * 32 + quad * 8);

    f32x4 co[2][4] = {};

    for (int k0 = 0; k0 < 2048; k0 += 128) {
        __syncthreads();
        #pragma unroll
        for (int i = 0; i < 4; ++i) {                 // K tile: 128 x 64
            int r = wave * 32 + i * 8 + (lane >> 3);
            int c = (lane & 7) ^ (r & 7);
            glds16(Kb + (size_t)(k0 + r) * 64 + c * 8,
                   &Ks[(wave * 32 + i * 8) * 64]);
        }
        #pragma unroll
        for (int i = 0; i < 4; ++i) {                 // Vt tile: 64 x 128
            int r = wave * 16 + i * 4 + (lane >> 4);
            int c = lane & 15;
            int cp = (c & 8) | ((c ^ r) & 7);
            glds16(Vb + (size_t)r * 2048 + k0 + cp * 8,
                   &Vs[(wave * 16 + i * 4) * 128]);
        }
        __syncthreads();

        // S^T tiles: rows=128 keys (8 chunks), cols = wave's 32 q (2 chunks).
        f32x4 st[8][2] = {};
        #pragma unroll
        for (int kc = 0; kc < 2; ++kc) {
            #pragma unroll
            for (int ki = 0; ki < 8; ++ki) {
                bf16x8 ak = *(const bf16x8*)&Ks[(ki * 16 + l16) * 64 +
                                                (((kc * 4 + quad) ^ (l16 & 7)) * 8)];
                #pragma unroll
                for (int mi = 0; mi < 2; ++mi)
                    st[ki][mi] = MFMA16(ak, aq[mi][kc], st[ki][mi]);
            }
        }

        // p = relu(s/8 + mask[key])^2; lane's 4 regs = 4 consecutive keys
        // -> one b64 store per (ki,mi) into wave-private Ps rows.
        #pragma unroll
        for (int ki = 0; ki < 8; ++ki) {
            floatx4 mk = *(const floatx4*)&mb[k0 + ki * 16 + quad * 4];
            #pragma unroll
            for (int mi = 0; mi < 2; ++mi) {
                bf16x4 pv;
                #pragma unroll
                for (int r = 0; r < 4; ++r) {
                    float sc = st[ki][mi][r] * 0.125f + mk[r];
                    sc = fmaxf(sc, 0.0f);
                    pv[r] = (__bf16)(sc * sc);
                }
                *(bf16x4*)&Ps[(wq + mi * 16 + l16) * 136 + ki * 16 + quad * 4] = pv;
            }
        }
        // No barrier: each wave reads back only rows it wrote (RAW via lgkmcnt).

        // ctx += P @ V, contraction over 128 keys in 4 chunks of 32.
        #pragma unroll
        for (int kc = 0; kc < 4; ++kc) {
            bf16x8 ap[2], bv4[4];
            #pragma unroll
            for (int mi = 0; mi < 2; ++mi)
                ap[mi] = *(const bf16x8*)&Ps[(wq + mi * 16 + l16) * 136 +
                                             kc * 32 + quad * 8];
            #pragma unroll
            for (int ni = 0; ni < 4; ++ni) {
                int rowv = ni * 16 + l16;
                int cl = kc * 4 + quad;
                int s = (cl & 8) | ((cl ^ rowv) & 7);
                bv4[ni] = *(const bf16x8*)&Vs[rowv * 128 + s * 8];
            }
            #pragma unroll
            for (int mi = 0; mi < 2; ++mi)
                #pragma unroll
                for (int ni = 0; ni < 4; ++ni)
                    co[mi][ni] = MFMA16(ap[mi], bv4[ni], co[mi][ni]);
        }
    }

    // Epilogue: out[b][s][h*64+d] fp32.
    #pragma unroll
    for (int mi = 0; mi < 2; ++mi)
        #pragma unroll
        for (int ni = 0; ni < 4; ++ni)
            #pragma unroll
            for (int r = 0; r < 4; ++r) {
                int s = q0 + wq + mi * 16 + quad * 4 + r;
                int d = ni * 16 + l16;
                out[(((size_t)b * 2048 + s) * 16 + h) * 64 + d] = co[mi][ni][r];
            }
}

// ---------------------------------------------------------------------------
extern "C" void kernel_launch(void* const* d_in, const int* in_sizes, int n_in,
                              void* d_out, int out_size, void* d_ws, size_t ws_size,
                              hipStream_t stream) {
    const float* hidden = (const float*)d_in[0];   // [4,2048,1024]
    const float* mask   = (const float*)d_in[1];   // [4,1,1,2048]
    const float* Wq     = (const float*)d_in[2];
    const float* bq     = (const float*)d_in[3];
    const float* Wk     = (const float*)d_in[4];
    const float* bk     = (const float*)d_in[5];
    const float* Wv     = (const float*)d_in[6];
    const float* bv     = (const float*)d_in[7];
    float* out = (float*)d_out;

    // Workspace layout (bf16): Q,K [64][2048][64]; Vt [64][64][2048];
    // Xb [8192][1024]; Wqb/Wkb/Wvb [1024][1024].  Total ~70 MB.
    __bf16* qws = (__bf16*)d_ws;
    __bf16* kws = qws + (size_t)64 * 2048 * 64;
    __bf16* vws = kws + (size_t)64 * 2048 * 64;
    __bf16* Xb  = vws + (size_t)64 * 2048 * 64;
    __bf16* Wqb = Xb  + (size_t)8192 * 1024;
    __bf16* Wkb = Wqb + (size_t)1024 * 1024;
    __bf16* Wvb = Wkb + (size_t)1024 * 1024;

    dim3 blk(256);
    convert_kernel<<<dim3(5632), blk, 0, stream>>>(hidden, Wq, Wk, Wv,
                                                   Xb, Wqb, Wkb, Wvb);
    qkv_gemm_kernel<<<dim3(24, 64), blk, 0, stream>>>(Xb, Wqb, Wkb, Wvb,
                                                      bq, bk, bv, qws, kws, vws);
    attn_kernel<<<dim3(16, 64), blk, 0, stream>>>(qws, kws, vws, mask, out);
}

// Round 3
// 299.566 us; speedup vs baseline: 1.3965x; 1.1117x over previous
//
#include <hip/hip_runtime.h>

// MI355X / gfx950. bf16 MFMA BERT attention with relu^2 "softmax".
// mfma_f32_16x16x32_bf16 layouts (HW-verified):
//   A: lane l holds A[m=l&15][k=(l>>4)*8+j]
//   B: lane l holds B[k=(l>>4)*8+j][n=l&15]
//   C/D: lane l reg r holds D[row=(l>>4)*4+r][col=l&15]
// Attention: S^T = K Q^T (C rows = keys); P round-trips through wave-private
// LDS (b64 writes / b128 reads, no barriers); PV computed as ctx^T = V^T P^T
// so ctx epilogue is float4 stores. K and V^T fragments load DIRECTLY from
// global (fragment layout = 8 contiguous elements of the k-dim) — no K/V LDS.

typedef __bf16 bf16x8 __attribute__((ext_vector_type(8)));
typedef __bf16 bf16x4 __attribute__((ext_vector_type(4)));
typedef float  f32x4  __attribute__((ext_vector_type(4)));
typedef float  floatx4 __attribute__((ext_vector_type(4)));

#define MFMA16(a, b, c) __builtin_amdgcn_mfma_f32_16x16x32_bf16(a, b, c, 0, 0, 0)

__device__ __forceinline__ void glds16(const __bf16* g, __bf16* l) {
    __builtin_amdgcn_global_load_lds(
        (const __attribute__((address_space(1))) void*)g,
        (__attribute__((address_space(3))) void*)l, 16, 0, 0);
}

// ---------------------------------------------------------------------------
// fp32 -> bf16 conversion: X (8M elems) then Wq/Wk/Wv (1M each).
// ---------------------------------------------------------------------------
__global__ __launch_bounds__(256) void convert_kernel(
    const float* __restrict__ X, const float* __restrict__ Wq,
    const float* __restrict__ Wk, const float* __restrict__ Wv,
    __bf16* __restrict__ Xb, __bf16* __restrict__ Wqb,
    __bf16* __restrict__ Wkb, __bf16* __restrict__ Wvb)
{
    int blk = blockIdx.x;
    const float* src; __bf16* dst; size_t base;
    if (blk < 4096)      { src = X;  dst = Xb;  base = (size_t)blk * 2048; }
    else if (blk < 4608) { src = Wq; dst = Wqb; base = (size_t)(blk - 4096) * 2048; }
    else if (blk < 5120) { src = Wk; dst = Wkb; base = (size_t)(blk - 4608) * 2048; }
    else                 { src = Wv; dst = Wvb; base = (size_t)(blk - 5120) * 2048; }
    size_t off = base + (size_t)threadIdx.x * 8;
    floatx4 a = *(const floatx4*)(src + off);
    floatx4 c = *(const floatx4*)(src + off + 4);
    bf16x8 o;
    o[0] = (__bf16)a[0]; o[1] = (__bf16)a[1]; o[2] = (__bf16)a[2]; o[3] = (__bf16)a[3];
    o[4] = (__bf16)c[0]; o[5] = (__bf16)c[1]; o[6] = (__bf16)c[2]; o[7] = (__bf16)c[3];
    *(bf16x8*)(dst + off) = o;
}

// ---------------------------------------------------------------------------
// Fused QKV GEMM: out = Xb @ Wb.T + bias. glds staging + XOR swizzle.
// blockIdx.x: 0-7 -> Q, 8-15 -> K, 16-23 -> V(transposed).
// Q/K mode: MFMA operands SWAPPED (A=W, B=X) so C rows = features -> each
// lane's 4 regs = 4 consecutive d -> b64 stores to [s][d].
// V mode: normal order, 4 regs = 4 consecutive s -> b64 stores to [d][s].
// ---------------------------------------------------------------------------
__global__ __launch_bounds__(256) void qkv_gemm_kernel(
    const __bf16* __restrict__ Xb,
    const __bf16* __restrict__ Wqb, const __bf16* __restrict__ Wkb,
    const __bf16* __restrict__ Wvb,
    const float* __restrict__ bq, const float* __restrict__ bk,
    const float* __restrict__ bv,
    __bf16* __restrict__ qws, __bf16* __restrict__ kws, __bf16* __restrict__ vws)
{
    __shared__ __bf16 As[128 * 64];
    __shared__ __bf16 Bs[128 * 64];

    const int tid  = threadIdx.x;
    const int lane = tid & 63;
    const int wave = tid >> 6;
    const int wm   = (wave >> 1) * 64;
    const int wn   = (wave & 1) * 64;
    const int quad = lane >> 4;
    const int l16  = lane & 15;
    const int m0   = blockIdx.y * 128;

    const int sel = blockIdx.x >> 3;
    const bool vmode = (sel == 2);
    const __bf16* Wb = (sel == 0) ? Wqb : (sel == 1) ? Wkb : Wvb;
    const float* bias = (sel == 0) ? bq : (sel == 1) ? bk : bv;
    __bf16* outp = (sel == 0) ? qws : (sel == 1) ? kws : vws;
    const int n0 = (blockIdx.x & 7) * 128;

    // Operand-role selection (tiles are layout-identical 128x64).
    const __bf16* Pa = vmode ? As : Bs;
    const __bf16* Pb = vmode ? Bs : As;
    const int woffA = vmode ? wm : wn;
    const int woffB = vmode ? wn : wm;

    f32x4 acc[4][4] = {};

    for (int k0 = 0; k0 < 1024; k0 += 64) {
        __syncthreads();
        #pragma unroll
        for (int i = 0; i < 4; ++i) {
            int r = wave * 32 + i * 8 + (lane >> 3);      // tile row 0..127
            int c = (lane & 7) ^ (r & 7);                 // swizzled k-chunk
            glds16(Xb + (size_t)(m0 + r) * 1024 + k0 + c * 8,
                   &As[(wave * 32 + i * 8) * 64]);
            glds16(Wb + (size_t)(n0 + r) * 1024 + k0 + c * 8,
                   &Bs[(wave * 32 + i * 8) * 64]);
        }
        __syncthreads();

        #pragma unroll
        for (int kk8 = 0; kk8 < 8; kk8 += 4) {            // two K=32 steps
            bf16x8 af[4], bfr[4];
            #pragma unroll
            for (int a = 0; a < 4; ++a)
                af[a] = *(const bf16x8*)&Pa[(woffA + a * 16 + l16) * 64 +
                                            (((kk8 + quad) ^ (l16 & 7)) * 8)];
            #pragma unroll
            for (int bb = 0; bb < 4; ++bb)
                bfr[bb] = *(const bf16x8*)&Pb[(woffB + bb * 16 + l16) * 64 +
                                              (((kk8 + quad) ^ (l16 & 7)) * 8)];
            #pragma unroll
            for (int a = 0; a < 4; ++a)
                #pragma unroll
                for (int bb = 0; bb < 4; ++bb)
                    acc[a][bb] = MFMA16(af[a], bfr[bb], acc[a][bb]);
        }
    }

    if (!vmode) {
        // C rows = W features (n), cols = X rows (m=s).
        #pragma unroll
        for (int a = 0; a < 4; ++a) {
            int n = n0 + woffA + a * 16 + quad * 4;       // 4-aligned
            floatx4 bv4 = *(const floatx4*)&bias[n];
            int h = n >> 6, d0 = n & 63;
            #pragma unroll
            for (int bb = 0; bb < 4; ++bb) {
                int m = m0 + woffB + bb * 16 + l16;
                int bt = m >> 11, s = m & 2047;
                bf16x4 o;
                #pragma unroll
                for (int r = 0; r < 4; ++r)
                    o[r] = (__bf16)(acc[a][bb][r] + bv4[r]);
                *(bf16x4*)&outp[((size_t)(bt * 16 + h) * 2048 + s) * 64 + d0] = o;
            }
        }
    } else {
        // C rows = X rows (m=s), cols = W features (n).
        #pragma unroll
        for (int a = 0; a < 4; ++a) {
            int m = m0 + woffA + a * 16 + quad * 4;       // 4-aligned, same bt
            int bt = m >> 11, s0 = m & 2047;
            #pragma unroll
            for (int bb = 0; bb < 4; ++bb) {
                int n = n0 + woffB + bb * 16 + l16;
                float bvv = bias[n];
                int h = n >> 6, d = n & 63;
                bf16x4 o;
                #pragma unroll
                for (int r = 0; r < 4; ++r)
                    o[r] = (__bf16)(acc[a][bb][r] + bvv);
                *(bf16x4*)&outp[((size_t)(bt * 16 + h) * 64 + d) * 2048 + s0] = o;
            }
        }
    }
}

// ---------------------------------------------------------------------------
// Attention: grid (8, 64); block = 4 waves, each owning 64 q-rows (q-block
// 256). K-loop over 64-key tiles. No __syncthreads, no K/V LDS:
//   S^T = K Q^T      (A = K frags from global, B = Q frags in registers)
//   P   -> wave-private LDS rows (b64 writes, b128 reads)
//   ctx^T = V^T P^T  (A = V^T frags from global, B = P frags from LDS)
// Epilogue: lane regs = 4 consecutive d -> float4 stores.
// ---------------------------------------------------------------------------
__global__ __launch_bounds__(256, 2) void attn_kernel(
    const __bf16* __restrict__ Q, const __bf16* __restrict__ K,
    const __bf16* __restrict__ Vt, const float* __restrict__ mask,
    float* __restrict__ out)
{
    __shared__ __bf16 Ps[256 * 72];    // 4 waves x [64 q][64 key + 8 pad]

    const int tid  = threadIdx.x;
    const int lane = tid & 63;
    const int wave = tid >> 6;
    const int quad = lane >> 4;
    const int l16  = lane & 15;
    const int bh   = blockIdx.y;
    const int b    = bh >> 4;
    const int h    = bh & 15;
    const int q0   = blockIdx.x * 256 + wave * 64;   // wave's q base

    const __bf16* Qb = Q  + (size_t)bh * 2048 * 64;
    const __bf16* Kb = K  + (size_t)bh * 2048 * 64;
    const __bf16* Vb = Vt + (size_t)bh * 64 * 2048;
    const float*  mb = mask + b * 2048;
    __bf16* Pw = &Ps[wave * 64 * 72];

    // Q fragments (B operand for S^T): lane n=l16 -> q, k = 8 contiguous d.
    bf16x8 aq[4][2];
    #pragma unroll
    for (int qi = 0; qi < 4; ++qi)
        #pragma unroll
        for (int kcd = 0; kcd < 2; ++kcd)
            aq[qi][kcd] = *(const bf16x8*)(Qb +
                (size_t)(q0 + qi * 16 + l16) * 64 + kcd * 32 + quad * 8);

    f32x4 co[4][4] = {};   // ctx^T: [d-tile][q-tile]

    for (int k0 = 0; k0 < 2048; k0 += 64) {
        // ---- S^T for 64 keys x 64 q ----
        f32x4 st[4][4] = {};
        #pragma unroll
        for (int kcd = 0; kcd < 2; ++kcd) {
            bf16x8 ak[4];
            #pragma unroll
            for (int ki = 0; ki < 4; ++ki)
                ak[ki] = *(const bf16x8*)(Kb +
                    (size_t)(k0 + ki * 16 + l16) * 64 + kcd * 32 + quad * 8);
            #pragma unroll
            for (int ki = 0; ki < 4; ++ki)
                #pragma unroll
                for (int qi = 0; qi < 4; ++qi)
                    st[ki][qi] = MFMA16(ak[ki], aq[qi][kcd], st[ki][qi]);
        }

        // ---- p = relu(s/8 + mask[key])^2 -> Pw[q][key] (b64 stores) ----
        #pragma unroll
        for (int ki = 0; ki < 4; ++ki) {
            floatx4 mk = *(const floatx4*)&mb[k0 + ki * 16 + quad * 4];
            #pragma unroll
            for (int qi = 0; qi < 4; ++qi) {
                bf16x4 pv;
                #pragma unroll
                for (int r = 0; r < 4; ++r) {
                    float x = st[ki][qi][r] * 0.125f + mk[r];
                    x = fmaxf(x, 0.0f);
                    pv[r] = (__bf16)(x * x);
                }
                *(bf16x4*)&Pw[(qi * 16 + l16) * 72 + ki * 16 + quad * 4] = pv;
            }
        }

        // ---- ctx^T += V^T P^T, contraction over 64 keys (2 chunks) ----
        #pragma unroll
        for (int kc = 0; kc < 2; ++kc) {
            bf16x8 av[4], bp[4];
            #pragma unroll
            for (int di = 0; di < 4; ++di)
                av[di] = *(const bf16x8*)(Vb +
                    (size_t)(di * 16 + l16) * 2048 + k0 + kc * 32 + quad * 8);
            #pragma unroll
            for (int qi = 0; qi < 4; ++qi)
                bp[qi] = *(const bf16x8*)&Pw[(qi * 16 + l16) * 72 +
                                             kc * 32 + quad * 8];
            #pragma unroll
            for (int di = 0; di < 4; ++di)
                #pragma unroll
                for (int qi = 0; qi < 4; ++qi)
                    co[di][qi] = MFMA16(av[di], bp[qi], co[di][qi]);
        }
    }

    // Epilogue: row = d = di*16+quad*4+r (consecutive), col = q = qi*16+l16.
    #pragma unroll
    for (int di = 0; di < 4; ++di) {
        int d0 = di * 16 + quad * 4;
        #pragma unroll
        for (int qi = 0; qi < 4; ++qi) {
            int q = q0 + qi * 16 + l16;
            *(floatx4*)&out[(((size_t)b * 2048 + q) * 16 + h) * 64 + d0] =
                co[di][qi];
        }
    }
}

// ---------------------------------------------------------------------------
extern "C" void kernel_launch(void* const* d_in, const int* in_sizes, int n_in,
                              void* d_out, int out_size, void* d_ws, size_t ws_size,
                              hipStream_t stream) {
    const float* hidden = (const float*)d_in[0];   // [4,2048,1024]
    const float* mask   = (const float*)d_in[1];   // [4,1,1,2048]
    const float* Wq     = (const float*)d_in[2];
    const float* bq     = (const float*)d_in[3];
    const float* Wk     = (const float*)d_in[4];
    const float* bk     = (const float*)d_in[5];
    const float* Wv     = (const float*)d_in[6];
    const float* bv     = (const float*)d_in[7];
    float* out = (float*)d_out;

    __bf16* qws = (__bf16*)d_ws;                       // [64][2048][64]
    __bf16* kws = qws + (size_t)64 * 2048 * 64;        // [64][2048][64]
    __bf16* vws = kws + (size_t)64 * 2048 * 64;        // [64][64][2048]
    __bf16* Xb  = vws + (size_t)64 * 2048 * 64;        // [8192][1024]
    __bf16* Wqb = Xb  + (size_t)8192 * 1024;
    __bf16* Wkb = Wqb + (size_t)1024 * 1024;
    __bf16* Wvb = Wkb + (size_t)1024 * 1024;

    dim3 blk(256);
    convert_kernel<<<dim3(5632), blk, 0, stream>>>(hidden, Wq, Wk, Wv,
                                                   Xb, Wqb, Wkb, Wvb);
    qkv_gemm_kernel<<<dim3(24, 64), blk, 0, stream>>>(Xb, Wqb, Wkb, Wvb,
                                                      bq, bk, bv, qws, kws, vws);
    attn_kernel<<<dim3(8, 64), blk, 0, stream>>>(qws, kws, vws, mask, out);
}